// Round 4
// baseline (590.730 us; speedup 1.0000x reference)
//
#include <hip/hip_runtime.h>
#include <cstdint>

#define S5 512
#define PLANE ((size_t)S5 * S5)   // 262144 elements per channel plane

typedef __attribute__((ext_vector_type(4))) float f32x4;
typedef __attribute__((ext_vector_type(8))) short bf16x8;

__device__ __forceinline__ unsigned short f2bf(float f) {
  union { float f; unsigned u; } v; v.f = f;
  unsigned r = v.u + 0x7fffu + ((v.u >> 16) & 1u);
  return (unsigned short)(r >> 16);
}
__device__ __forceinline__ unsigned pack2(float a, float b) {
  return (unsigned)f2bf(a) | ((unsigned)f2bf(b) << 16);
}
__device__ __forceinline__ float bf2f(unsigned short h) {
  union { unsigned u; float f; } v; v.u = ((unsigned)h) << 16;
  return v.f;
}
// hi/lo error-free-ish split: x ≈ bf16(hi) + bf16(lo), lo = bf16(x - hi)
__device__ __forceinline__ void pack2hl(float a, float b, unsigned& hi, unsigned& lo) {
  unsigned short ah = f2bf(a), bh = f2bf(b);
  unsigned short al = f2bf(a - bf2f(ah)), bl = f2bf(b - bf2f(bh));
  hi = (unsigned)ah | ((unsigned)bh << 16);
  lo = (unsigned)al | ((unsigned)bl << 16);
}

// ---------------------------------------------------------------- K0: weights
// wTab[256][128]: rows 0-127 = Wa^T, rows 128-255 = Wb^T
// wgT[128][128]:  wgT[y][z]  = Wg[z][y]
// woutT[128][128]: woutT[zo][c] = Wout[c][zo]
__global__ void k0_prep(const float* __restrict__ Wa, const float* __restrict__ Wb,
                        const float* __restrict__ Wg, const float* __restrict__ Wout,
                        unsigned short* __restrict__ wTab, unsigned short* __restrict__ wgT,
                        unsigned short* __restrict__ woutT) {
  int t = blockIdx.x * 256 + threadIdx.x;  // 0..65535
  if (t < 32768) {
    int cg = t >> 7, zz = t & 127;
    const float* W = (cg < 128) ? Wa : Wb;
    int c = cg & 127;
    wTab[t] = f2bf(W[zz * 128 + c]);
  } else if (t < 49152) {
    int u = t - 32768; int y = u >> 7, zz = u & 127;
    wgT[u] = f2bf(Wg[zz * 128 + y]);
  } else if (t < 65536) {
    int u = t - 49152; int zo = u >> 7, c = u & 127;
    woutT[u] = f2bf(Wout[c * 128 + zo]);
  }
}

// ------------------------------------------------- K1: LN(z) + a/b projection
// 64 z-rows per block, 256 cols (a|b). Weights live as register B-fragments.
// Epilogue: LDS re-tile -> each thread writes 128B contiguous per channel plane.
__launch_bounds__(256, 2)
__global__ void k1_ln_proj(const float* __restrict__ z,
                           const float* __restrict__ ln_w, const float* __restrict__ ln_b,
                           const float* __restrict__ ba, const float* __restrict__ bb,
                           const unsigned short* __restrict__ wTab,
                           unsigned short* __restrict__ aT, unsigned short* __restrict__ bT) {
  __shared__ unsigned short zs[64][136];   // stride 68 dw === 4 mod 32 -> balanced banks
  __shared__ unsigned obuf[32][257];       // [pos-pair][outch], stride 257 -> conflict-free
  __shared__ float lnw[128], lnb[128];
  int t = threadIdx.x;
  int lane = t & 63, w = t >> 6;
  int row0 = blockIdx.x * 64;

  if (t < 128) lnw[t] = ln_w[t];
  else lnb[t - 128] = ln_b[t - 128];

  // weight B-fragments: wave w owns global col-tiles w*4 .. w*4+3
  bf16x8 wf[4][4];
#pragma unroll
  for (int tt = 0; tt < 4; ++tt) {
    int gct = w * 4 + tt;
    int wr = gct * 16 + (lane & 15);
#pragma unroll
    for (int kk = 0; kk < 4; ++kk)
      wf[tt][kk] = *reinterpret_cast<const bf16x8*>(wTab + wr * 128 + kk * 32 + ((lane >> 4) << 3));
  }
  __syncthreads();  // lnw/lnb ready

  // LayerNorm: 4 threads per row (32 ch each), shuffle-reduce within 4-lane group
  {
    int r = t >> 2, q = t & 3;
    const float* zp = z + (size_t)(row0 + r) * 128 + q * 32;
    float v[32]; float s = 0.f, s2 = 0.f;
#pragma unroll
    for (int i = 0; i < 8; ++i) {
      f32x4 x = *reinterpret_cast<const f32x4*>(zp + i * 4);
      v[i * 4] = x[0]; v[i * 4 + 1] = x[1]; v[i * 4 + 2] = x[2]; v[i * 4 + 3] = x[3];
      s  += x[0] + x[1] + x[2] + x[3];
      s2 += x[0] * x[0] + x[1] * x[1] + x[2] * x[2] + x[3] * x[3];
    }
    s  += __shfl_xor(s, 1);  s  += __shfl_xor(s, 2);
    s2 += __shfl_xor(s2, 1); s2 += __shfl_xor(s2, 2);
    float mu = s * (1.f / 128.f);
    float var = s2 * (1.f / 128.f) - mu * mu;
    float rstd = rsqrtf(var + 1e-5f);
    unsigned pk[16];
#pragma unroll
    for (int i = 0; i < 16; ++i) {
      int c = q * 32 + i * 2;
      float a0 = (v[i * 2] - mu) * rstd * lnw[c] + lnb[c];
      float a1 = (v[i * 2 + 1] - mu) * rstd * lnw[c + 1] + lnb[c + 1];
      pk[i] = pack2(a0, a1);
    }
#pragma unroll
    for (int i = 0; i < 4; ++i)
      *reinterpret_cast<uint4*>(&zs[r][q * 32 + i * 8]) =
          make_uint4(pk[i * 4], pk[i * 4 + 1], pk[i * 4 + 2], pk[i * 4 + 3]);
  }
  __syncthreads();

  f32x4 acc[4][4];
#pragma unroll
  for (int a = 0; a < 4; ++a)
#pragma unroll
    for (int b2 = 0; b2 < 4; ++b2) { f32x4 zv = {0.f, 0.f, 0.f, 0.f}; acc[a][b2] = zv; }

#pragma unroll
  for (int kk = 0; kk < 4; ++kk) {
    bf16x8 af[4];
#pragma unroll
    for (int rt = 0; rt < 4; ++rt)
      af[rt] = *reinterpret_cast<const bf16x8*>(&zs[rt * 16 + (lane & 15)][kk * 32 + ((lane >> 4) << 3)]);
#pragma unroll
    for (int rt = 0; rt < 4; ++rt)
#pragma unroll
      for (int tt = 0; tt < 4; ++tt)
        acc[rt][tt] = __builtin_amdgcn_mfma_f32_16x16x32_bf16(af[rt], wf[tt][kk], acc[rt][tt], 0, 0, 0);
  }

  // epilogue stage 1: acc (+bias) -> obuf[pos/2][oc] as packed bf16 pairs
#pragma unroll
  for (int tt = 0; tt < 4; ++tt) {
    int gct = w * 4 + tt;
    int oc = gct * 16 + (lane & 15);         // 0..255 (a: 0-127, b: 128-255)
    int m = gct >> 3;
    int c = oc & 127;
    float bias = (m ? bb : ba)[c];
#pragma unroll
    for (int rt = 0; rt < 4; ++rt) {
      int q = rt * 8 + ((lane >> 4) << 1);   // pos-pair index
      f32x4 v = acc[rt][tt];
      obuf[q][oc]     = pack2(v[0] + bias, v[1] + bias);
      obuf[q + 1][oc] = pack2(v[2] + bias, v[3] + bias);
    }
  }
  __syncthreads();

  // epilogue stage 2: thread t owns out-channel t -> 128B contiguous plane write
  {
    int m = t >> 7, c = t & 127;
    unsigned short* plane = (m ? bT : aT) + (size_t)c * PLANE + row0;
    unsigned r[32];
#pragma unroll
    for (int q = 0; q < 32; ++q) r[q] = obuf[q][t];
#pragma unroll
    for (int u = 0; u < 8; ++u)
      *reinterpret_cast<uint4*>(plane + u * 8) =
          make_uint4(r[u * 4], r[u * 4 + 1], r[u * 4 + 2], r[u * 4 + 3]);
  }
}

// --------------------------------------------- K2: 128 per-channel GEMM-BT
// ab[i,j,c] = sum_k a[i,k,c] b[j,k,c]; per channel: C = A * B^T, 128x128 tile, BK=64
// XCD-cluster swizzle: XCD x owns channels x*16..x*16+15 (L2-resident panels)
__launch_bounds__(256, 2)
__global__ void k2_gemm(const unsigned short* __restrict__ aT,
                        const unsigned short* __restrict__ bT,
                        unsigned short* __restrict__ abT) {
  __shared__ unsigned short As[128][72];   // stride 36 dw === 4 mod 32 -> balanced banks
  __shared__ unsigned short Bs[128][72];
  int t = threadIdx.x, lane = t & 63, w = t >> 6;
  int bid = ((blockIdx.x & 7) << 8) | (blockIdx.x >> 3);  // bijective: 2048 = 8*256
  int c = bid >> 4;
  int tid = bid & 15;
  int i0 = (tid >> 2) * 128, j0 = (tid & 3) * 128;
  const unsigned short* Ap = aT + (size_t)c * PLANE;
  const unsigned short* Bp = bT + (size_t)c * PLANE;
  int rw = (w >> 1) * 64, cw = (w & 1) * 64;

  f32x4 acc[4][4];
#pragma unroll
  for (int a = 0; a < 4; ++a)
#pragma unroll
    for (int b2 = 0; b2 < 4; ++b2) { f32x4 zv = {0.f, 0.f, 0.f, 0.f}; acc[a][b2] = zv; }

  int sr = t >> 3;          // staging row within 32-row group
  int sc = (t & 7) * 8;     // staging col (elements)
  for (int k0 = 0; k0 < 512; k0 += 64) {
#pragma unroll
    for (int p = 0; p < 4; ++p) {
      int r = p * 32 + sr;
      *reinterpret_cast<uint4*>(&As[r][sc]) =
          *reinterpret_cast<const uint4*>(Ap + (size_t)(i0 + r) * 512 + k0 + sc);
      *reinterpret_cast<uint4*>(&Bs[r][sc]) =
          *reinterpret_cast<const uint4*>(Bp + (size_t)(j0 + r) * 512 + k0 + sc);
    }
    __syncthreads();
#pragma unroll
    for (int kk = 0; kk < 2; ++kk) {
      bf16x8 af[4], bfr[4];
#pragma unroll
      for (int rt = 0; rt < 4; ++rt)
        af[rt] = *reinterpret_cast<const bf16x8*>(&As[rw + rt * 16 + (lane & 15)][kk * 32 + ((lane >> 4) << 3)]);
#pragma unroll
      for (int ct = 0; ct < 4; ++ct)
        bfr[ct] = *reinterpret_cast<const bf16x8*>(&Bs[cw + ct * 16 + (lane & 15)][kk * 32 + ((lane >> 4) << 3)]);
#pragma unroll
      for (int rt = 0; rt < 4; ++rt)
#pragma unroll
        for (int ct = 0; ct < 4; ++ct)
          acc[rt][ct] = __builtin_amdgcn_mfma_f32_16x16x32_bf16(af[rt], bfr[ct], acc[rt][ct], 0, 0, 0);
    }
    __syncthreads();
  }

  unsigned short* Op = abT + (size_t)c * PLANE;
#pragma unroll
  for (int rt = 0; rt < 4; ++rt)
#pragma unroll
    for (int ct = 0; ct < 4; ++ct) {
      int j = j0 + cw + ct * 16 + (lane & 15);
      int ib = i0 + rw + rt * 16 + ((lane >> 4) << 2);
      f32x4 v = acc[rt][ct];
#pragma unroll
      for (int rr = 0; rr < 4; ++rr)
        Op[(size_t)(ib + rr) * 512 + j] = f2bf(v[rr]);
    }
}

// ------------------- K3: transpose abT tile -> LN(ab)*Wout; LN(z)*Wg sigmoid; gate
// Block = 64 positions (row i, cols j0..j0+63). 4 waves x 16 positions.
// All LN in registers; A-operands hi/lo split-bf16 (2 MFMAs) for fp32-grade accuracy;
// weights read from global; single 16KB XOR-swizzled LDS tile; ONE barrier.
__launch_bounds__(256, 2)
__global__ void k3_final(const float* __restrict__ z,
                         const unsigned short* __restrict__ abT,
                         const unsigned short* __restrict__ wgT,
                         const unsigned short* __restrict__ woutT,
                         const float* __restrict__ ln_w, const float* __restrict__ ln_b,
                         const float* __restrict__ lno_w, const float* __restrict__ lno_b,
                         const float* __restrict__ bg, const float* __restrict__ bout,
                         float* __restrict__ out) {
  __shared__ unsigned XabU[64][64];   // [pos][chan-pair], chunk-XOR swizzled, 16KB
  int t = threadIdx.x, lane = t & 63, w = t >> 6;
  int i = blockIdx.x >> 3;
  int j0 = (blockIdx.x & 7) * 64;

  // ---- fill: abT planes -> XabU (two planes packed per dword; conflict-free)
  {
    int c2 = lane;                    // channel pair 0..63
    int p0 = w * 16;
    const unsigned short* sA = abT + (size_t)(2 * c2) * PLANE + (size_t)i * 512 + j0 + p0;
    const unsigned short* sB = sA + PLANE;
    unsigned short la[16], lb[16];
    *reinterpret_cast<uint4*>(la)     = *reinterpret_cast<const uint4*>(sA);
    *reinterpret_cast<uint4*>(la + 8) = *reinterpret_cast<const uint4*>(sA + 8);
    *reinterpret_cast<uint4*>(lb)     = *reinterpret_cast<const uint4*>(sB);
    *reinterpret_cast<uint4*>(lb + 8) = *reinterpret_cast<const uint4*>(sB + 8);
#pragma unroll
    for (int k = 0; k < 16; ++k) {
      int p = p0 + k;
      int col = ((((c2 >> 2) ^ (p & 7)) & 15) << 2) | (c2 & 3);  // chunk-XOR swizzle
      XabU[p][col] = (unsigned)la[k] | ((unsigned)lb[k] << 16);
    }
  }

  int ks = lane >> 4;                 // k-slot 0..3
  int prow16 = lane & 15;             // position within wave's 16
  int jpos = j0 + w * 16 + prow16;
  size_t growA = (size_t)i * 512 + jpos;

  // ---- z-LN fully in registers -> hi/lo A-frags
  bf16x8 pzh[4], pzl[4];
  {
    const float* zp = z + growA * 128;
    float x[4][8]; float s = 0.f, s2 = 0.f;
#pragma unroll
    for (int kk = 0; kk < 4; ++kk) {
      int cb = ks * 8 + kk * 32;
      f32x4 a0 = *reinterpret_cast<const f32x4*>(zp + cb);
      f32x4 a1 = *reinterpret_cast<const f32x4*>(zp + cb + 4);
#pragma unroll
      for (int e = 0; e < 4; ++e) { x[kk][e] = a0[e]; x[kk][4 + e] = a1[e]; }
      s  += a0[0] + a0[1] + a0[2] + a0[3] + a1[0] + a1[1] + a1[2] + a1[3];
      s2 += a0[0]*a0[0] + a0[1]*a0[1] + a0[2]*a0[2] + a0[3]*a0[3]
          + a1[0]*a1[0] + a1[1]*a1[1] + a1[2]*a1[2] + a1[3]*a1[3];
    }
    s  += __shfl_xor(s, 16);  s  += __shfl_xor(s, 32);
    s2 += __shfl_xor(s2, 16); s2 += __shfl_xor(s2, 32);
    float mu = s * (1.f / 128.f);
    float var = s2 * (1.f / 128.f) - mu * mu;
    float rstd = rsqrtf(var + 1e-5f);
#pragma unroll
    for (int kk = 0; kk < 4; ++kk) {
      int cb = ks * 8 + kk * 32;
      f32x4 w0 = *reinterpret_cast<const f32x4*>(ln_w + cb);
      f32x4 w1 = *reinterpret_cast<const f32x4*>(ln_w + cb + 4);
      f32x4 b0 = *reinterpret_cast<const f32x4*>(ln_b + cb);
      f32x4 b1 = *reinterpret_cast<const f32x4*>(ln_b + cb + 4);
      float y0 = (x[kk][0]-mu)*rstd*w0[0]+b0[0], y1 = (x[kk][1]-mu)*rstd*w0[1]+b0[1];
      float y2 = (x[kk][2]-mu)*rstd*w0[2]+b0[2], y3 = (x[kk][3]-mu)*rstd*w0[3]+b0[3];
      float y4 = (x[kk][4]-mu)*rstd*w1[0]+b1[0], y5 = (x[kk][5]-mu)*rstd*w1[1]+b1[1];
      float y6 = (x[kk][6]-mu)*rstd*w1[2]+b1[2], y7 = (x[kk][7]-mu)*rstd*w1[3]+b1[3];
      union { unsigned u[4]; bf16x8 v; } H, L;
      pack2hl(y0, y1, H.u[0], L.u[0]);
      pack2hl(y2, y3, H.u[1], L.u[1]);
      pack2hl(y4, y5, H.u[2], L.u[2]);
      pack2hl(y6, y7, H.u[3], L.u[3]);
      pzh[kk] = H.v; pzl[kk] = L.v;
    }
  }

  // ---- g-GEMM (doesn't touch Xab; overlaps the transpose): D[pos][y] = zln . WgT
  f32x4 ga[8];
#pragma unroll
  for (int q = 0; q < 8; ++q) { f32x4 zv = {0.f, 0.f, 0.f, 0.f}; ga[q] = zv; }
#pragma unroll
  for (int kk = 0; kk < 4; ++kk) {
    int cb = ks * 8 + kk * 32;
#pragma unroll
    for (int ct = 0; ct < 8; ++ct) {
      bf16x8 bfr = *reinterpret_cast<const bf16x8*>(wgT + (ct * 16 + prow16) * 128 + cb);
      ga[ct] = __builtin_amdgcn_mfma_f32_16x16x32_bf16(pzh[kk], bfr, ga[ct], 0, 0, 0);
      ga[ct] = __builtin_amdgcn_mfma_f32_16x16x32_bf16(pzl[kk], bfr, ga[ct], 0, 0, 0);
    }
  }
#pragma unroll
  for (int ct = 0; ct < 8; ++ct) {
    float b4 = bg[ct * 16 + prow16];
#pragma unroll
    for (int rr = 0; rr < 4; ++rr)
      ga[ct][rr] = 1.f / (1.f + expf(-(ga[ct][rr] + b4)));
  }

  __syncthreads();   // Xab transpose complete

  // ---- ab-LN in registers from swizzled Xab -> hi/lo A-frags
  bf16x8 pah[4], pal[4];
  {
    int p = w * 16 + prow16;
    const unsigned* row = &XabU[p][0];
    float x[4][8]; float s = 0.f, s2 = 0.f;
#pragma unroll
    for (int kk = 0; kk < 4; ++kk) {
      int chunk = ((ks + 4 * kk) ^ (p & 7)) & 15;
      bf16x8 raw = *reinterpret_cast<const bf16x8*>(row + (chunk << 2));
#pragma unroll
      for (int e = 0; e < 8; ++e) {
        float f = bf2f((unsigned short)raw[e]);
        x[kk][e] = f; s += f; s2 += f * f;
      }
    }
    s  += __shfl_xor(s, 16);  s  += __shfl_xor(s, 32);
    s2 += __shfl_xor(s2, 16); s2 += __shfl_xor(s2, 32);
    float mu = s * (1.f / 128.f);
    float var = s2 * (1.f / 128.f) - mu * mu;
    float rstd = rsqrtf(var + 1e-5f);
#pragma unroll
    for (int kk = 0; kk < 4; ++kk) {
      int cb = ks * 8 + kk * 32;
      f32x4 w0 = *reinterpret_cast<const f32x4*>(lno_w + cb);
      f32x4 w1 = *reinterpret_cast<const f32x4*>(lno_w + cb + 4);
      f32x4 b0 = *reinterpret_cast<const f32x4*>(lno_b + cb);
      f32x4 b1 = *reinterpret_cast<const f32x4*>(lno_b + cb + 4);
      float y0 = (x[kk][0]-mu)*rstd*w0[0]+b0[0], y1 = (x[kk][1]-mu)*rstd*w0[1]+b0[1];
      float y2 = (x[kk][2]-mu)*rstd*w0[2]+b0[2], y3 = (x[kk][3]-mu)*rstd*w0[3]+b0[3];
      float y4 = (x[kk][4]-mu)*rstd*w1[0]+b1[0], y5 = (x[kk][5]-mu)*rstd*w1[1]+b1[1];
      float y6 = (x[kk][6]-mu)*rstd*w1[2]+b1[2], y7 = (x[kk][7]-mu)*rstd*w1[3]+b1[3];
      union { unsigned u[4]; bf16x8 v; } H, L;
      pack2hl(y0, y1, H.u[0], L.u[0]);
      pack2hl(y2, y3, H.u[1], L.u[1]);
      pack2hl(y4, y5, H.u[2], L.u[2]);
      pack2hl(y6, y7, H.u[3], L.u[3]);
      pah[kk] = H.v; pal[kk] = L.v;
    }
  }

  // ---- out-GEMM: D[pos][zo] = LN(ab) . WoutT  (hi/lo A)
  f32x4 oa[8];
#pragma unroll
  for (int q = 0; q < 8; ++q) { f32x4 zv = {0.f, 0.f, 0.f, 0.f}; oa[q] = zv; }
#pragma unroll
  for (int kk = 0; kk < 4; ++kk) {
    int cb = ks * 8 + kk * 32;
#pragma unroll
    for (int ct = 0; ct < 8; ++ct) {
      bf16x8 bfr = *reinterpret_cast<const bf16x8*>(woutT + (ct * 16 + prow16) * 128 + cb);
      oa[ct] = __builtin_amdgcn_mfma_f32_16x16x32_bf16(pah[kk], bfr, oa[ct], 0, 0, 0);
      oa[ct] = __builtin_amdgcn_mfma_f32_16x16x32_bf16(pal[kk], bfr, oa[ct], 0, 0, 0);
    }
  }

  // ---- gate + bias + store fp32 (per instr: 4 x 64B full lines)
#pragma unroll
  for (int ct = 0; ct < 8; ++ct) {
    int zc = ct * 16 + prow16;
    float bo = bout[zc];
#pragma unroll
    for (int rr = 0; rr < 4; ++rr) {
      int prow = ks * 4 + rr;                      // C/D row = position
      size_t o = ((size_t)i * 512 + j0 + w * 16 + prow) * 128 + zc;
      out[o] = ga[ct][rr] * (oa[ct][rr] + bo);
    }
  }
}

extern "C" void kernel_launch(void* const* d_in, const int* in_sizes, int n_in,
                              void* d_out, int out_size, void* d_ws, size_t ws_size,
                              hipStream_t stream) {
  const float* z     = (const float*)d_in[0];
  const float* ln_w  = (const float*)d_in[1];
  const float* ln_b  = (const float*)d_in[2];
  const float* Wa    = (const float*)d_in[3];
  const float* ba    = (const float*)d_in[4];
  const float* Wb    = (const float*)d_in[5];
  const float* bb    = (const float*)d_in[6];
  const float* Wg    = (const float*)d_in[7];
  const float* bg    = (const float*)d_in[8];
  const float* lno_w = (const float*)d_in[9];
  const float* lno_b = (const float*)d_in[10];
  const float* Wout  = (const float*)d_in[11];
  const float* bout  = (const float*)d_in[12];
  float* out = (float*)d_out;

  char* ws = (char*)d_ws;
  unsigned short* aT    = (unsigned short*)(ws);                  // 67,108,864 B
  unsigned short* bT    = (unsigned short*)(ws + 67108864);       // 67,108,864 B
  unsigned short* abT   = (unsigned short*)(ws + 134217728);      // 67,108,864 B
  unsigned short* wTab  = (unsigned short*)(ws + 201326592);      // 65,536 B
  unsigned short* wgT   = (unsigned short*)(ws + 201392128);      // 32,768 B
  unsigned short* woutT = (unsigned short*)(ws + 201424896);      // 32,768 B

  k0_prep<<<256, 256, 0, stream>>>(Wa, Wb, Wg, Wout, wTab, wgT, woutT);
  k1_ln_proj<<<4096, 256, 0, stream>>>(z, ln_w, ln_b, ba, bb, wTab, aT, bT);
  k2_gemm<<<2048, 256, 0, stream>>>(aT, bT, abT);
  k3_final<<<4096, 256, 0, stream>>>(z, abT, wgT, woutT, ln_w, ln_b, lno_w, lno_b,
                                     bg, bout, out);
}